// Round 3
// baseline (145.301 us; speedup 1.0000x reference)
//
#include <hip/hip_runtime.h>
#include <hip/hip_bf16.h>
#include <stdint.h>

#define P    300
#define HID  128
#define NG   1000

typedef __attribute__((ext_vector_type(8))) short bf16x8;
typedef __attribute__((ext_vector_type(4))) float f32x4;

// Swizzled bf16 W^T. Slot fkey holds weights for column perm(fkey):
// W2 (pass1): perm(fkey) = u*32 + 2*(fkey&15) + ((fkey>>4)&1), u=fkey>>5.
// W3 (pass2): natural. chunk(fkey,kc) at slot fkey*16 + (kc ^ (fkey&15)).
__device__ short g_wsw[2 * HID * HID];

__device__ __forceinline__ short f2bf(float f) {
    union { float f; uint32_t u; } v; v.f = f;
    uint32_t r = v.u + 0x7fffu + ((v.u >> 16) & 1u);   // RNE
    return (short)(r >> 16);
}
__device__ __forceinline__ float bf2f(short s) {
    union { uint32_t u; float f; } v; v.u = ((uint32_t)(uint16_t)s) << 16;
    return v.f;
}
__device__ __forceinline__ uint32_t pkbf2(float a, float b) {   // low=a, high=b
    union { __hip_bfloat162 h; uint32_t u; } cv;
    cv.h = __float22bfloat162_rn(float2{a, b});
    return cv.u;
}
__device__ __forceinline__ float unpk(int v, int ft) {
    return bf2f((short)(ft ? (((uint32_t)v) >> 16) : (v & 0xffff)));
}

__global__ __launch_bounds__(256) void k_prep(const float* __restrict__ W2,
                                              const float* __restrict__ W3) {
    int b = blockIdx.x;                       // 16 blocks
    const bool perm = (b < 8);
    const float* W = perm ? W2 : W3;
    short* dst = g_wsw + (perm ? 0 : HID * HID);
    int t    = (b & 7) * 256 + threadIdx.x;   // 0..2047 chunks
    int fkey = t >> 4;
    int kc   = t & 15;
    int fsrc;
    if (perm) {
        int u = fkey >> 5, ft = (fkey >> 4) & 1, l = fkey & 15;
        fsrc = u * 32 + 2 * l + ft;
    } else fsrc = fkey;
    bf16x8 o;
    #pragma unroll
    for (int j = 0; j < 8; ++j)
        o[j] = f2bf(W[(kc * 8 + j) * HID + fsrc]);
    *(bf16x8*)&dst[(fkey * 16 + (kc ^ (fkey & 15))) * 8] = o;
}

// ring-average + bias + relu over 4 consecutive node-rows held in regs
__device__ __forceinline__ void avg_epi(const float* G, float vp0, float vn3,
                                        float b, float* o) {
    o[0] = (vp0  + G[0] + G[1]) * (1.0f / 3.0f) + b;
    o[1] = (G[0] + G[1] + G[2]) * (1.0f / 3.0f) + b;
    o[2] = (G[1] + G[2] + G[3]) * (1.0f / 3.0f) + b;
    o[3] = (G[2] + G[3] + vn3 ) * (1.0f / 3.0f) + b;
    #pragma unroll
    for (int i = 0; i < 4; ++i) o[i] = o[i] > 0.f ? o[i] : 0.f;
}

// One GCN layer over one graph in LDS, 8 waves = 2 node-groups x 4 waves.
// Each group covers all 128 features (2 ft-tiles/wave, b32 paired stores).
//   group 0: epilogue tiles 9..0  (nodes   0..159), BACKWARD pipeline
//   group 1: epilogue tiles 10..18 (nodes 160..299), FORWARD pipeline
// Each group duplicate-computes the boundary tiles it needs (G10/G18 for g0,
// G9/G0 for g1) so there is no cross-group data exchange. 12 barrier-aligned
// steps/pass (!POOL): {mfma reads} -> barrier -> {epilogue stores}; schedule
// chosen so every store of tile T is after ALL reads of T (incl. ring wrap).
template<int POOL>
__device__ __forceinline__ void run_pass(short* __restrict__ buf,
                                         const short* __restrict__ wbase,
                                         const float* __restrict__ bias,
                                         float* __restrict__ pool, int tid) {
    const int lane = tid & 63, wvall = tid >> 6;
    const int grp = wvall >> 2, wv = wvall & 3;
    const int q = lane >> 4, lm = lane & 15;
    const int ftg0 = wv * 2;
    bf16x8 wf[2][4];
    #pragma unroll
    for (int ft = 0; ft < 2; ++ft) {
        int fkey = (ftg0 + ft) * 16 + lm;
        #pragma unroll
        for (int kk = 0; kk < 4; ++kk)
            wf[ft][kk] = *(const bf16x8*)&wbase[(fkey * 16 + ((4 * kk + q) ^ lm)) * 8];
    }
    float biaf[2];
    #pragma unroll
    for (int ft = 0; ft < 2; ++ft)
        biaf[ft] = POOL ? bias[(ftg0 + ft) * 16 + lm] : bias[wv * 32 + 2 * lm + ft];
    const int sA  = (q == 0) ? (48 + lm) : (lane - 16);  // fwd: row above / row15(E)
    const int sAb = (lane - 16) & 63;                    // bwd: row above (q>0 only)
    const int sB  = (lane + 16) & 63;
    const int fpair = wv * 32 + 2 * lm;       // even physical feature (pass1)
    const int kcs = fpair >> 3, offs = fpair & 7;

    float psum[2] = {0.f, 0.f};

    auto mfma_tile = [&](int t, f32x4* G) {
        const short* tb = buf + t * 2048;
        G[0] = f32x4{0.f, 0.f, 0.f, 0.f};
        G[1] = f32x4{0.f, 0.f, 0.f, 0.f};
        #pragma unroll
        for (int kk = 0; kk < 4; ++kk) {
            bf16x8 af = *(const bf16x8*)&tb[(lm * 16 + ((4 * kk + q) ^ lm)) * 8];
            G[0] = __builtin_amdgcn_mfma_f32_16x16x32_bf16(af, wf[0][kk], G[0], 0, 0, 0);
            G[1] = __builtin_amdgcn_mfma_f32_16x16x32_bf16(af, wf[1][kk], G[1], 0, 0, 0);
        }
    };
    auto store_rows = [&](int T, float (&o)[2][4]) {
        #pragma unroll
        for (int i = 0; i < 4; ++i) {
            int node = T * 16 + q * 4 + i;
            *(uint32_t*)&buf[(node * 16 + (kcs ^ (node & 15))) * 8 + offs] =
                pkbf2(o[0][i], o[1][i]);
        }
    };
    auto accum = [&](float (&o)[2][4]) {
        #pragma unroll
        for (int ft = 0; ft < 2; ++ft)
            psum[ft] += o[ft][0] + o[ft][1] + o[ft][2] + o[ft][3];
    };

    f32x4 Gc[2], Gn[2];

    if (grp == 0) {
        // ===== group 0: tiles 10,9,8,...,0, then 18; epi 9..0 backward =====
        float c0[2];                          // row0 of tile T+1 (bcast, bf16-rnd)
        mfma_tile(10, Gn);
        if (!POOL) __syncthreads();                                   // s=0
        {
            int vZ = __shfl((int)pkbf2(Gn[0][0], Gn[1][0]), lm, 64);
            c0[0] = unpk(vZ, 0); c0[1] = unpk(vZ, 1);
        }
        mfma_tile(9, Gc);
        if (!POOL) __syncthreads();                                   // s=1
        for (int s = 2; s <= 10; ++s) {
            mfma_tile(10 - s, Gn);            // Gn = G[T-1]
            if (!POOL) __syncthreads();                               // s
            int T = 11 - s;                   // E = Gc = G[T]
            uint32_t uE3 = pkbf2(Gc[0][3], Gc[1][3]);
            uint32_t uE0 = pkbf2(Gc[0][0], Gc[1][0]);
            uint32_t uN3 = pkbf2(Gn[0][3], Gn[1][3]);
            int vA = __shfl((int)uE3, sAb, 64);      // row q*4-1   (q>0)
            int vB = __shfl((int)uE0, sB, 64);       // row (q+1)*4 (q<3)
            int vZ = __shfl((int)uE0, lm, 64);       // row0(E) -> next c0
            int vP = __shfl((int)uN3, 48 + lm, 64);  // row15 of G[T-1]
            float o[2][4];
            #pragma unroll
            for (int ft = 0; ft < 2; ++ft) {
                float vp0 = (q == 0) ? unpk(vP, ft) : unpk(vA, ft);
                float vn3 = (q == 3) ? c0[ft] : unpk(vB, ft);
                avg_epi((const float*)&Gc[ft], vp0, vn3, biaf[ft], o[ft]);
                c0[ft] = unpk(vZ, ft);
            }
            if (POOL) accum(o); else store_rows(T, o);
            Gc[0] = Gn[0]; Gc[1] = Gn[1];
        }
        mfma_tile(18, Gn);                    // for node299 = G18.row11
        if (!POOL) __syncthreads();                                   // s=11
        {
            uint32_t uE3 = pkbf2(Gc[0][3], Gc[1][3]);   // E = G0
            uint32_t uE0 = pkbf2(Gc[0][0], Gc[1][0]);
            uint32_t uN3 = pkbf2(Gn[0][3], Gn[1][3]);
            int vA = __shfl((int)uE3, sAb, 64);
            int vB = __shfl((int)uE0, sB, 64);
            int vP = __shfl((int)uN3, 32 + lm, 64);  // G18.row11 = node299
            float o[2][4];
            #pragma unroll
            for (int ft = 0; ft < 2; ++ft) {
                float vp0 = (q == 0) ? unpk(vP, ft) : unpk(vA, ft);
                float vn3 = (q == 3) ? c0[ft] : unpk(vB, ft);   // c0 = row0(G1)
                avg_epi((const float*)&Gc[ft], vp0, vn3, biaf[ft], o[ft]);
            }
            if (POOL) accum(o); else store_rows(0, o);
        }
    } else {
        // ===== group 1: tiles 9,0,10,11,...,18; epi 10..18 forward =====
        float c15[2], g0r0[2];
        mfma_tile(9, Gn);                     // c15 seed = G9.row15
        if (!POOL) __syncthreads();                                   // s=0
        {
            int v = __shfl((int)pkbf2(Gn[0][3], Gn[1][3]), 48 + lm, 64);
            c15[0] = unpk(v, 0); c15[1] = unpk(v, 1);
        }
        mfma_tile(0, Gn);                     // node0 for tile-18 wrap
        if (!POOL) __syncthreads();                                   // s=1
        g0r0[0] = __shfl(Gn[0][0], lm, 64);
        g0r0[1] = __shfl(Gn[1][0], lm, 64);
        mfma_tile(10, Gc);
        if (!POOL) __syncthreads();                                   // s=2
        for (int s = 3; s <= 10; ++s) {
            mfma_tile(8 + s, Gn);             // Gn = G[T+1]
            if (!POOL) __syncthreads();                               // s
            int T = s + 7;                    // E = Gc = G[T]
            uint32_t uE3 = pkbf2(Gc[0][3], Gc[1][3]);
            uint32_t uE0 = pkbf2(Gc[0][0], Gc[1][0]);
            uint32_t uN0 = pkbf2(Gn[0][0], Gn[1][0]);
            int vA = __shfl((int)uE3, sA, 64);
            int vB = __shfl((int)uE0, sB, 64);
            int vC = __shfl((int)uN0, lm, 64);       // row0 of G[T+1]
            float o[2][4];
            #pragma unroll
            for (int ft = 0; ft < 2; ++ft) {
                float bpA = unpk(vA, ft);
                float vp0 = (q == 0) ? c15[ft] : bpA;
                float vn3 = (q == 3) ? unpk(vC, ft) : unpk(vB, ft);
                avg_epi((const float*)&Gc[ft], vp0, vn3, biaf[ft], o[ft]);
                c15[ft] = bpA;
            }
            if (POOL) accum(o); else store_rows(T, o);
            Gc[0] = Gn[0]; Gc[1] = Gn[1];
        }
        if (!POOL) __syncthreads();                                   // s=11
        {   // tail: tile 18 (q<3 valid; node299.next = node0)
            uint32_t uE3 = pkbf2(Gc[0][3], Gc[1][3]);
            uint32_t uE0 = pkbf2(Gc[0][0], Gc[1][0]);
            int vA = __shfl((int)uE3, sA, 64);
            int vB = __shfl((int)uE0, sB, 64);
            float o[2][4];
            #pragma unroll
            for (int ft = 0; ft < 2; ++ft) {
                float bpA = unpk(vA, ft);
                float vp0 = (q == 0) ? c15[ft] : bpA;
                float vn3 = (q == 2) ? g0r0[ft] : unpk(vB, ft);
                avg_epi((const float*)&Gc[ft], vp0, vn3, biaf[ft], o[ft]);
            }
            if (q < 3) {
                if (POOL) accum(o); else store_rows(18, o);
            }
        }
    }

    if (POOL) {
        #pragma unroll
        for (int ft = 0; ft < 2; ++ft) {
            psum[ft] += __shfl_xor(psum[ft], 16, 64);
            psum[ft] += __shfl_xor(psum[ft], 32, 64);
        }
        if (q == 0) {
            pool[grp * 128 + ftg0 * 16 + lm]      = psum[0];
            pool[grp * 128 + ftg0 * 16 + 16 + lm] = psum[1];
        }
    }
}

// One block (512 thr, 8 waves) per graph.
// LDS budget: round-2's 81408 B silently dropped residency to 1 block/CU
// (OccupancyPercent ~20, dur consistent with 4 sequential rounds) even
// though 2x81408=162816 <= 163840 -- usable per-CU LDS is slightly below
// 160 KiB (reserve in [1.0, 3.0] KiB). 80384 B is HW-proven to fit twice
// (round-0 kernel). This version: 77824 (buf) + 2400 (scr) = 80224 B.
__global__ __launch_bounds__(512, 2) void k_graph(
        const float* __restrict__ x,
        const float* __restrict__ W1,  const float* __restrict__ b1,
        const float* __restrict__ b2v, const float* __restrict__ b3v,
        const float* __restrict__ fw1, const float* __restrict__ fb1,
        const float* __restrict__ fw2, const float* __restrict__ fb2,
        float* __restrict__ out) {
    __shared__ __align__(16) short buf[304 * HID];   // 77824 B, chunk-swizzled
    __shared__ __align__(16) float scr[600];         // 2400 B
    float* xs    = scr;          // 600 (layer-1 only, dead after)
    float* poolv = scr;          // 256 = poolA(g0) | poolB(g1)
    float* parts = scr + 256;    // 256 (FC stage-1; overlaps xs tail, dead)
    float* s1    = scr;          // 128 (FC stage-2; overlaps poolv, dead)

    const int g = blockIdx.x, tid = threadIdx.x;

    if (tid < 150) *(float4*)&xs[tid * 4] = *(const float4*)&x[g * 600 + tid * 4];
    __syncthreads();

    // ---- layer 1: buf <- relu(avg3(x) @ W1 + b1); rows 300..303 zeroed ----
    {
        const int kc1 = tid & 15;
        const int n0  = tid >> 4;            // 0..31
        float w1x[8], w1y[8], b1v[8];
        #pragma unroll
        for (int j = 0; j < 8; ++j) {
            w1x[j] = W1[kc1 * 8 + j];
            w1y[j] = W1[HID + kc1 * 8 + j];
            b1v[j] = b1[kc1 * 8 + j];
        }
        #pragma unroll
        for (int it = 0; it < 10; ++it) {
            int node = it * 32 + n0;         // 0..319
            if (node < 304) {
                uint32_t w[4] = {0u, 0u, 0u, 0u};
                if (node < P) {
                    int prev = (node == 0)     ? P - 1 : node - 1;
                    int next = (node == P - 1) ? 0     : node + 1;
                    float2 xp = *(const float2*)&xs[2 * prev];
                    float2 xc = *(const float2*)&xs[2 * node];
                    float2 xn = *(const float2*)&xs[2 * next];
                    float ax = (xp.x + xc.x + xn.x) * (1.f / 3.f);
                    float ay = (xp.y + xc.y + xn.y) * (1.f / 3.f);
                    #pragma unroll
                    for (int jj = 0; jj < 4; ++jj) {
                        float va = ax * w1x[2*jj]   + ay * w1y[2*jj]   + b1v[2*jj];
                        float vb = ax * w1x[2*jj+1] + ay * w1y[2*jj+1] + b1v[2*jj+1];
                        va = va > 0.f ? va : 0.f;
                        vb = vb > 0.f ? vb : 0.f;
                        w[jj] = pkbf2(va, vb);
                    }
                }
                *(uint4*)&buf[(node * 16 + (kc1 ^ (node & 15))) * 8] =
                    uint4{w[0], w[1], w[2], w[3]};
            }
        }
    }
    __syncthreads();

    run_pass<0>(buf, g_wsw,             b2v, poolv, tid);   // h1 -> h2 in place
    __syncthreads();
    run_pass<1>(buf, g_wsw + HID * HID, b3v, poolv, tid);   // h2 -> pooled sums
    __syncthreads();

    // ---- FC head (tiny; 256 active threads keep parts at 256 floats) ----
    if (tid < 256) {
        int f = tid & 127, half = tid >> 7;
        float p = 0.f;
        const float* fw1c = fw1 + f;
        #pragma unroll 4
        for (int k = half * 64; k < half * 64 + 64; ++k)
            p += (poolv[k] + poolv[128 + k]) * fw1c[k * 128];
        parts[half * 128 + f] = p;
    }
    __syncthreads();
    if (tid < 128) {
        float o1 = fb1[tid] + (parts[tid] + parts[128 + tid]) * (1.0f / 300.0f);
        s1[tid] = o1 > 0.f ? o1 : 0.f;       // s1 aliases poolv (dead now)
    }
    __syncthreads();
    if (tid < 128) {
        int o = tid >> 6, ln = tid & 63;
        float v = s1[ln] * fw2[ln * 2 + o] + s1[ln + 64] * fw2[(ln + 64) * 2 + o];
        #pragma unroll
        for (int off = 1; off <= 32; off <<= 1)
            v += __shfl_xor(v, off, 64);
        if (ln == 0) out[g * 2 + o] = v + fb2[o];
    }
}

extern "C" void kernel_launch(void* const* d_in, const int* in_sizes, int n_in,
                              void* d_out, int out_size, void* d_ws, size_t ws_size,
                              hipStream_t stream) {
    const float* x   = (const float*)d_in[0];
    const float* W1  = (const float*)d_in[3];
    const float* b1  = (const float*)d_in[4];
    const float* W2  = (const float*)d_in[5];
    const float* b2  = (const float*)d_in[6];
    const float* W3  = (const float*)d_in[7];
    const float* b3  = (const float*)d_in[8];
    const float* fw1 = (const float*)d_in[9];
    const float* fb1 = (const float*)d_in[10];
    const float* fw2 = (const float*)d_in[11];
    const float* fb2 = (const float*)d_in[12];
    float* out = (float*)d_out;

    k_prep <<<dim3(16), dim3(256), 0, stream>>>(W2, W3);
    k_graph<<<dim3(NG), dim3(512), 0, stream>>>(x, W1, b1, b2, b3,
                                                fw1, fb1, fw2, fb2, out);
}

// Round 4
// 123.266 us; speedup vs baseline: 1.1788x; 1.1788x over previous
//
#include <hip/hip_runtime.h>
#include <hip/hip_bf16.h>
#include <stdint.h>

#define P    300
#define HID  128
#define NG   1000
#define NTL  19          // 16-node tiles (304 rows, 300 valid)

typedef __attribute__((ext_vector_type(8))) short bf16x8;
typedef __attribute__((ext_vector_type(4))) float f32x4;

// Swizzled bf16 W^T. Slot fkey holds weights for column perm(fkey):
// W2 (pass1): perm(fkey) = u*32 + 2*(fkey&15) + ((fkey>>4)&1), u=fkey>>5.
// W3 (pass2): natural. chunk(fkey,kc) at slot fkey*16 + (kc ^ (fkey&15)).
__device__ short g_wsw[2 * HID * HID];

__device__ __forceinline__ short f2bf(float f) {
    union { float f; uint32_t u; } v; v.f = f;
    uint32_t r = v.u + 0x7fffu + ((v.u >> 16) & 1u);   // RNE
    return (short)(r >> 16);
}
__device__ __forceinline__ float bf2f(short s) {
    union { uint32_t u; float f; } v; v.u = ((uint32_t)(uint16_t)s) << 16;
    return v.f;
}
__device__ __forceinline__ uint32_t pkbf2(float a, float b) {   // low=a, high=b
    union { __hip_bfloat162 h; uint32_t u; } cv;
    cv.h = __float22bfloat162_rn(float2{a, b});
    return cv.u;
}
__device__ __forceinline__ float unpk(int v, int ft) {
    return bf2f((short)(ft ? (((uint32_t)v) >> 16) : (v & 0xffff)));
}

__global__ __launch_bounds__(256) void k_prep(const float* __restrict__ W2,
                                              const float* __restrict__ W3) {
    int b = blockIdx.x;                       // 16 blocks
    const bool perm = (b < 8);
    const float* W = perm ? W2 : W3;
    short* dst = g_wsw + (perm ? 0 : HID * HID);
    int t    = (b & 7) * 256 + threadIdx.x;   // 0..2047 chunks
    int fkey = t >> 4;
    int kc   = t & 15;
    int fsrc;
    if (perm) {
        int u = fkey >> 5, ft = (fkey >> 4) & 1, l = fkey & 15;
        fsrc = u * 32 + 2 * l + ft;
    } else fsrc = fkey;
    bf16x8 o;
    #pragma unroll
    for (int j = 0; j < 8; ++j)
        o[j] = f2bf(W[(kc * 8 + j) * HID + fsrc]);
    *(bf16x8*)&dst[(fkey * 16 + (kc ^ (fkey & 15))) * 8] = o;
}

// ring-average + bias + relu over 4 consecutive node-rows held in regs
__device__ __forceinline__ void avg_epi(const float* G, float vp0, float vn3,
                                        float b, float* o) {
    o[0] = (vp0  + G[0] + G[1]) * (1.0f / 3.0f) + b;
    o[1] = (G[0] + G[1] + G[2]) * (1.0f / 3.0f) + b;
    o[2] = (G[1] + G[2] + G[3]) * (1.0f / 3.0f) + b;
    o[3] = (G[2] + G[3] + vn3 ) * (1.0f / 3.0f) + b;
    #pragma unroll
    for (int i = 0; i < 4; ++i) o[i] = o[i] > 0.f ? o[i] : 0.f;
}

// One GCN layer over one graph in LDS; 4 waves, each owning 2 ft-tiles
// (32 features). 3-phase schedule with only TWO barriers per store-pass
// (round-0 had 10; barriers were the latency wall at MfmaUtil 14%):
//   phase A: MFMA tiles {10..18, 0} -> regs GH       (reads only)
//   barrier
//   phase B: for i=0..8: MFMA tile 9-i -> GL[i]      (reads {9..1})
//            + epilogue/STORE tile 10+i (+ tile 0)   (stores {10..18,0})
//            read-set and store-set DISJOINT -> race-free by the barrier.
//   barrier
//   phase C: epilogue/STORE tiles 1..9 from GL       (stores only)
// GH dies as GL grows -> peak ~150-180 VGPR. POOL pass: same code, no
// stores, no barriers. Numerics identical to round-0 (packed-bf16
// neighbor shuffles via the c15 carry trick).
template<int POOL>
__device__ __forceinline__ void run_pass(short* __restrict__ buf,
                                         const short* __restrict__ wbase,
                                         const float* __restrict__ bias,
                                         float* __restrict__ pool, int tid) {
    const int lane = tid & 63, wv = tid >> 6, q = lane >> 4, lm = lane & 15;
    const int ftg0 = wv * 2;
    bf16x8 wf[2][4];
    #pragma unroll
    for (int ft = 0; ft < 2; ++ft) {
        int fkey = (ftg0 + ft) * 16 + lm;
        #pragma unroll
        for (int kk = 0; kk < 4; ++kk)
            wf[ft][kk] = *(const bf16x8*)&wbase[(fkey * 16 + ((4 * kk + q) ^ lm)) * 8];
    }
    float biaf[2];
    #pragma unroll
    for (int ft = 0; ft < 2; ++ft)
        biaf[ft] = POOL ? bias[(ftg0 + ft) * 16 + lm] : bias[wv * 32 + 2 * lm + ft];
    const int sA = (q == 0) ? (48 + lm) : (lane - 16);  // r15 carry / row above
    const int sB = (lane + 16) & 63;                    // row below (q<3)
    const int fpair = wv * 32 + 2 * lm;       // even physical feature (pass1)
    const int kcs = fpair >> 3, offs = fpair & 7;

    float psum[2] = {0.f, 0.f};

    auto mfma_tile = [&](int t, f32x4* G) {
        const short* tb = buf + t * 2048;
        G[0] = f32x4{0.f, 0.f, 0.f, 0.f};
        G[1] = f32x4{0.f, 0.f, 0.f, 0.f};
        #pragma unroll
        for (int kk = 0; kk < 4; ++kk) {
            bf16x8 af = *(const bf16x8*)&tb[(lm * 16 + ((4 * kk + q) ^ lm)) * 8];
            G[0] = __builtin_amdgcn_mfma_f32_16x16x32_bf16(af, wf[0][kk], G[0], 0, 0, 0);
            G[1] = __builtin_amdgcn_mfma_f32_16x16x32_bf16(af, wf[1][kk], G[1], 0, 0, 0);
        }
    };
    auto store_rows = [&](int T, float (&o)[2][4]) {
        #pragma unroll
        for (int i = 0; i < 4; ++i) {
            int node = T * 16 + q * 4 + i;
            *(uint32_t*)&buf[(node * 16 + (kcs ^ (node & 15))) * 8 + offs] =
                pkbf2(o[0][i], o[1][i]);
        }
    };
    auto accum = [&](float (&o)[2][4]) {
        #pragma unroll
        for (int ft = 0; ft < 2; ++ft)
            psum[ft] += o[ft][0] + o[ft][1] + o[ft][2] + o[ft][3];
    };

    float c15[2];
    // mid-ring epilogue of tile T: E = G[T], uN0 = packed r0 of G[T+1].
    auto epi_mid = [&](const f32x4 (&E)[2], uint32_t uN0, float (&o)[2][4]) {
        uint32_t uE3 = pkbf2(E[0][3], E[1][3]);
        uint32_t uE0 = pkbf2(E[0][0], E[1][0]);
        int vA = __shfl((int)uE3, sA, 64);
        int vB = __shfl((int)uE0, sB, 64);
        int vC = __shfl((int)uN0, lm, 64);
        #pragma unroll
        for (int ft = 0; ft < 2; ++ft) {
            float bpA = unpk(vA, ft);
            float vp0 = (q == 0) ? c15[ft] : bpA;
            float vn3 = (q == 3) ? unpk(vC, ft) : unpk(vB, ft);
            avg_epi((const float*)&E[ft], vp0, vn3, biaf[ft], o[ft]);
            c15[ft] = bpA;          // this tile's r15 -> next tile's vp0(q==0)
        }
    };

    f32x4 GH[10][2];   // GH[k] = G[10+k] for k<9; GH[9] = G[0]
    f32x4 GL[9][2];    // GL[i] = G[9-i]

    // ---- phase A: MFMA tiles 10..18 and 0 (reads only) ----
    #pragma unroll
    for (int k = 0; k < 9; ++k) mfma_tile(10 + k, GH[k]);
    mfma_tile(0, GH[9]);
    if (!POOL) __syncthreads();

    // ---- phase B: MFMA 9..1 interleaved with epi/store of 10..18, 0 ----
    #pragma unroll
    for (int i = 0; i < 9; ++i) {
        mfma_tile(9 - i, GL[i]);
        if (i == 0) {   // seed c15 = G9 r15 (node 159)
            int v = __shfl((int)pkbf2(GL[0][0][3], GL[0][1][3]), 48 + lm, 64);
            c15[0] = unpk(v, 0); c15[1] = unpk(v, 1);
        }
        if (i < 8) {    // tiles 10..17: generic mid-ring
            float o[2][4];
            uint32_t uN0 = pkbf2(GH[i + 1][0][0], GH[i + 1][1][0]);
            epi_mid(GH[i], uN0, o);
            if (POOL) accum(o); else store_rows(10 + i, o);
        } else {
            // tile 18 (rows 288..303, valid to 299; q==2,i==3 wraps to node 0)
            float o18[2][4];
            uint32_t uE3 = pkbf2(GH[8][0][3], GH[8][1][3]);
            uint32_t uE0 = pkbf2(GH[8][0][0], GH[8][1][0]);
            uint32_t uZ0 = pkbf2(GH[9][0][0], GH[9][1][0]);   // G0 r0 (node 0)
            int vA = __shfl((int)uE3, sA, 64);
            int vB = __shfl((int)uE0, sB, 64);
            int vZ = __shfl((int)uZ0, lm, 64);
            #pragma unroll
            for (int ft = 0; ft < 2; ++ft) {
                float bpA = unpk(vA, ft);
                float vp0 = (q == 0) ? c15[ft] : bpA;             // node 287
                float vn3 = (q == 2) ? unpk(vZ, ft) : unpk(vB, ft);
                avg_epi((const float*)&GH[8][ft], vp0, vn3, biaf[ft], o18[ft]);
            }
            if (q < 3) { if (POOL) accum(o18); else store_rows(18, o18); }
            // tile 0 (vp0 q==0: node 299 = G18 r11 -> lane 32+lm, reg3)
            float o0[2][4];
            uint32_t uF3 = pkbf2(GH[9][0][3], GH[9][1][3]);
            int vA0 = __shfl((int)uF3, (lane - 16) & 63, 64);
            int vB0 = __shfl((int)uZ0, sB, 64);
            int vP  = __shfl((int)uE3, 32 + lm, 64);              // G18 r11
            uint32_t uG1 = pkbf2(GL[8][0][0], GL[8][1][0]);       // G1 r0
            int vN = __shfl((int)uG1, lm, 64);
            #pragma unroll
            for (int ft = 0; ft < 2; ++ft) {
                float vp0 = (q == 0) ? unpk(vP, ft) : unpk(vA0, ft);
                float vn3 = (q == 3) ? unpk(vN, ft) : unpk(vB0, ft);
                avg_epi((const float*)&GH[9][ft], vp0, vn3, biaf[ft], o0[ft]);
            }
            if (POOL) accum(o0); else store_rows(0, o0);
        }
    }
    if (!POOL) __syncthreads();

    // ---- phase C: epi/store tiles 1..9 (stores only) ----
    {   // seed c15 = G0 r15 (node 15)
        int v = __shfl((int)pkbf2(GH[9][0][3], GH[9][1][3]), 48 + lm, 64);
        c15[0] = unpk(v, 0); c15[1] = unpk(v, 1);
    }
    #pragma unroll
    for (int T = 1; T <= 9; ++T) {
        float o[2][4];
        uint32_t uN0 = (T < 9) ? pkbf2(GL[8 - T][0][0], GL[8 - T][1][0])
                               : pkbf2(GH[0][0][0], GH[0][1][0]);   // G10 r0
        epi_mid(GL[9 - T], uN0, o);
        if (POOL) accum(o); else store_rows(T, o);
    }

    if (POOL) {
        #pragma unroll
        for (int ft = 0; ft < 2; ++ft) {
            psum[ft] += __shfl_xor(psum[ft], 16, 64);
            psum[ft] += __shfl_xor(psum[ft], 32, 64);
        }
        if (q == 0) {
            pool[ftg0 * 16 + lm]      = psum[0];
            pool[ftg0 * 16 + 16 + lm] = psum[1];
        }
    }
}

// One block (256 thr, 4 waves) per graph. LDS 80384 B (HW-proven 2/CU).
// launch_bounds(256,2): VGPR cap 256 under either 2nd-arg semantics;
// the 3-phase run_pass peaks ~150-180 VGPR.
__global__ __launch_bounds__(256, 2) void k_graph(
        const float* __restrict__ x,
        const float* __restrict__ W1,  const float* __restrict__ b1,
        const float* __restrict__ b2v, const float* __restrict__ b3v,
        const float* __restrict__ fw1, const float* __restrict__ fb1,
        const float* __restrict__ fw2, const float* __restrict__ fb2,
        float* __restrict__ out) {
    __shared__ __align__(16) short buf[304 * HID];   // 77824 B, chunk-swizzled
    __shared__ __align__(16) float scr[640];         // 2560 B -> total 80384
    float* xs    = scr;          // 600 (layer-1 only)
    float* pool  = scr;          // 128
    float* parts = scr + 128;    // 256
    float* s1    = scr + 384;    // 128

    const int g = blockIdx.x, tid = threadIdx.x;

    if (tid < 150) *(float4*)&xs[tid * 4] = *(const float4*)&x[g * 600 + tid * 4];
    __syncthreads();

    // ---- layer 1: buf <- relu(avg3(x) @ W1 + b1); rows 300..303 zeroed ----
    {
        const int kc1 = tid & 15;
        const int n0  = tid >> 4;
        float w1x[8], w1y[8], b1v[8];
        #pragma unroll
        for (int j = 0; j < 8; ++j) {
            w1x[j] = W1[kc1 * 8 + j];
            w1y[j] = W1[HID + kc1 * 8 + j];
            b1v[j] = b1[kc1 * 8 + j];
        }
        #pragma unroll
        for (int it = 0; it < NTL; ++it) {
            int node = it * 16 + n0;
            uint32_t w[4] = {0u, 0u, 0u, 0u};
            if (node < P) {
                int prev = (node == 0)     ? P - 1 : node - 1;
                int next = (node == P - 1) ? 0     : node + 1;
                float2 xp = *(const float2*)&xs[2 * prev];
                float2 xc = *(const float2*)&xs[2 * node];
                float2 xn = *(const float2*)&xs[2 * next];
                float ax = (xp.x + xc.x + xn.x) * (1.f / 3.f);
                float ay = (xp.y + xc.y + xn.y) * (1.f / 3.f);
                #pragma unroll
                for (int jj = 0; jj < 4; ++jj) {
                    float va = ax * w1x[2*jj]   + ay * w1y[2*jj]   + b1v[2*jj];
                    float vb = ax * w1x[2*jj+1] + ay * w1y[2*jj+1] + b1v[2*jj+1];
                    va = va > 0.f ? va : 0.f;
                    vb = vb > 0.f ? vb : 0.f;
                    w[jj] = pkbf2(va, vb);
                }
            }
            *(uint4*)&buf[(node * 16 + (kc1 ^ (node & 15))) * 8] =
                uint4{w[0], w[1], w[2], w[3]};
        }
    }
    __syncthreads();

    run_pass<0>(buf, g_wsw,             b2v, pool, tid);   // h1 -> h2 in place
    __syncthreads();
    run_pass<1>(buf, g_wsw + HID * HID, b3v, pool, tid);   // h2 -> pooled sums
    __syncthreads();

    // ---- FC head ----
    {
        int f = tid & 127, half = tid >> 7;
        float p = 0.f;
        const float* fw1c = fw1 + f;
        #pragma unroll 4
        for (int k = half * 64; k < half * 64 + 64; ++k)
            p += pool[k] * fw1c[k * 128];
        parts[half * 128 + f] = p;
    }
    __syncthreads();
    if (tid < 128) {
        float o1 = fb1[tid] + (parts[tid] + parts[128 + tid]) * (1.0f / 300.0f);
        s1[tid] = o1 > 0.f ? o1 : 0.f;
    }
    __syncthreads();
    if (tid < 128) {
        int o = tid >> 6, ln = tid & 63;
        float v = s1[ln] * fw2[ln * 2 + o] + s1[ln + 64] * fw2[(ln + 64) * 2 + o];
        #pragma unroll
        for (int off = 1; off <= 32; off <<= 1)
            v += __shfl_xor(v, off, 64);
        if (ln == 0) out[g * 2 + o] = v + fb2[o];
    }
}

extern "C" void kernel_launch(void* const* d_in, const int* in_sizes, int n_in,
                              void* d_out, int out_size, void* d_ws, size_t ws_size,
                              hipStream_t stream) {
    const float* x   = (const float*)d_in[0];
    const float* W1  = (const float*)d_in[3];
    const float* b1  = (const float*)d_in[4];
    const float* W2  = (const float*)d_in[5];
    const float* b2  = (const float*)d_in[6];
    const float* W3  = (const float*)d_in[7];
    const float* b3  = (const float*)d_in[8];
    const float* fw1 = (const float*)d_in[9];
    const float* fb1 = (const float*)d_in[10];
    const float* fw2 = (const float*)d_in[11];
    const float* fb2 = (const float*)d_in[12];
    float* out = (float*)d_out;

    k_prep <<<dim3(16), dim3(256), 0, stream>>>(W2, W3);
    k_graph<<<dim3(NG), dim3(256), 0, stream>>>(x, W1, b1, b2, b3,
                                                fw1, fb1, fw2, fb2, out);
}